// Round 1
// baseline (225.388 us; speedup 1.0000x reference)
//
#include <hip/hip_runtime.h>
#include <hip/hip_bf16.h>

// TopPool: out[b,c,h,w] = max_{h'>=h} x[b,c,h',w]  (reverse cummax over axis 2)
// x shape (32, 256, 128, 128) fp32, w innermost.
// One thread per (plane, w4) column; plane = b*C + c, w4 = group of 4 floats.

#define H 128
#define W4 32   // 128 floats / 4 per float4

__global__ __launch_bounds__(256) void toppool_kernel(const float4* __restrict__ x,
                                                      float4* __restrict__ out) {
    const int tid   = blockIdx.x * blockDim.x + threadIdx.x;   // 0 .. 262143
    const int w4    = tid & (W4 - 1);
    const int plane = tid >> 5;                                 // b*C + c

    const size_t base = (size_t)plane * H * W4 + w4;
    const float4* xp = x + base;
    float4* op = out + base;

    float4 m = xp[(H - 1) * W4];
    op[(H - 1) * W4] = m;

    #pragma unroll 4
    for (int h = H - 2; h >= 0; --h) {
        float4 v = xp[h * W4];
        m.x = fmaxf(m.x, v.x);
        m.y = fmaxf(m.y, v.y);
        m.z = fmaxf(m.z, v.z);
        m.w = fmaxf(m.w, v.w);
        op[h * W4] = m;
    }
}

extern "C" void kernel_launch(void* const* d_in, const int* in_sizes, int n_in,
                              void* d_out, int out_size, void* d_ws, size_t ws_size,
                              hipStream_t stream) {
    const float4* x = (const float4*)d_in[0];
    float4* out = (float4*)d_out;

    // total threads = (32*256 planes) * 32 float4-columns = 262144
    const int total = 32 * 256 * W4;
    const int block = 256;
    const int grid = total / block;   // 1024
    toppool_kernel<<<grid, block, 0, stream>>>(x, out);
}

// Round 3
// 203.914 us; speedup vs baseline: 1.1053x; 1.1053x over previous
//
#include <hip/hip_runtime.h>
#include <hip/hip_bf16.h>

// TopPool: out[b,c,h,w] = max_{h'>=h} x[b,c,h',w]  (reverse cummax over axis 2)
// x shape (32, 256, 128, 128) fp32, w innermost.
// One thread per (plane, w4) column; plane = b*C + c, w4 = group of 4 floats.
// Streaming kernel: compulsory traffic 0.537 GB read + 0.537 GB write.
// nt (nontemporal) hints on both streams: data is touched exactly once,
// don't let L2 retain it. Unroll 8 for 8 independent 16B loads in flight
// per thread (fmax chain is dependent, loads are not).
// NOTE: __builtin_nontemporal_* requires a NATIVE vector type, not
// HIP_vector_type<float,4> — use clang ext_vector_type.

#define H 128
#define W4 32   // 128 floats / 4 per float4

typedef float f32x4 __attribute__((ext_vector_type(4)));

__global__ __launch_bounds__(256) void toppool_kernel(const f32x4* __restrict__ x,
                                                      f32x4* __restrict__ out) {
    const int tid   = blockIdx.x * blockDim.x + threadIdx.x;   // 0 .. 262143
    const int w4    = tid & (W4 - 1);
    const int plane = tid >> 5;                                 // b*C + c

    const size_t base = (size_t)plane * H * W4 + w4;
    const f32x4* xp = x + base;
    f32x4* op = out + base;

    f32x4 m = __builtin_nontemporal_load(&xp[(H - 1) * W4]);
    __builtin_nontemporal_store(m, &op[(H - 1) * W4]);

    #pragma unroll 8
    for (int h = H - 2; h >= 0; --h) {
        f32x4 v = __builtin_nontemporal_load(&xp[h * W4]);
        m.x = fmaxf(m.x, v.x);
        m.y = fmaxf(m.y, v.y);
        m.z = fmaxf(m.z, v.z);
        m.w = fmaxf(m.w, v.w);
        __builtin_nontemporal_store(m, &op[h * W4]);
    }
}

extern "C" void kernel_launch(void* const* d_in, const int* in_sizes, int n_in,
                              void* d_out, int out_size, void* d_ws, size_t ws_size,
                              hipStream_t stream) {
    const f32x4* x = (const f32x4*)d_in[0];
    f32x4* out = (f32x4*)d_out;

    // total threads = (32*256 planes) * 32 float4-columns = 262144
    const int total = 32 * 256 * W4;
    const int block = 256;
    const int grid = total / block;   // 1024
    toppool_kernel<<<grid, block, 0, stream>>>(x, out);
}

// Round 4
// 193.717 us; speedup vs baseline: 1.1635x; 1.0526x over previous
//
#include <hip/hip_runtime.h>
#include <hip/hip_bf16.h>

// TopPool: out[b,c,h,w] = max_{h'>=h} x[b,c,h',w]  (reverse cummax over axis 2)
// x shape (32, 256, 128, 128) fp32, w innermost.
// One thread per (plane, w4) column. Compulsory traffic 0.537+0.537 GB.
// 2-deep software pipeline: prefetch next 8 h-steps into `nxt` BEFORE the
// current batch's fmax+store chain, so 8 loads are always in flight
// regardless of the serial running-max dependency. All register-array
// indices are compile-time constants (runtime idx -> scratch).

#define H 128
#define W4 32   // 128 floats / 4 per float4
#define U 8     // batch size (h-steps per pipeline stage)
#define NB (H / U)  // 16 batches

typedef float f32x4 __attribute__((ext_vector_type(4)));

__device__ __forceinline__ f32x4 fmax4(f32x4 a, f32x4 b) {
    f32x4 r;
    r.x = fmaxf(a.x, b.x);
    r.y = fmaxf(a.y, b.y);
    r.z = fmaxf(a.z, b.z);
    r.w = fmaxf(a.w, b.w);
    return r;
}

__global__ __launch_bounds__(256) void toppool_kernel(const f32x4* __restrict__ x,
                                                      f32x4* __restrict__ out) {
    const int tid   = blockIdx.x * blockDim.x + threadIdx.x;   // 0 .. 262143
    const int w4    = tid & (W4 - 1);
    const int plane = tid >> 5;                                 // b*C + c

    const size_t base = (size_t)plane * H * W4 + w4;
    const f32x4* xp = x + base;
    f32x4* op = out + base;

    f32x4 cur[U], nxt[U];

    // prologue: load h = 127..120
    #pragma unroll
    for (int i = 0; i < U; ++i)
        cur[i] = __builtin_nontemporal_load(&xp[(H - 1 - i) * W4]);

    f32x4 m;
    m.x = -__builtin_huge_valf();
    m.y = -__builtin_huge_valf();
    m.z = -__builtin_huge_valf();
    m.w = -__builtin_huge_valf();

    // main: batches 0 .. NB-2, each prefetches the following batch first
    for (int b = 0; b < NB - 1; ++b) {
        const int hbase = H - 1 - b * U;
        // issue next batch's loads (independent of the fmax chain)
        #pragma unroll
        for (int i = 0; i < U; ++i)
            nxt[i] = __builtin_nontemporal_load(&xp[(hbase - U - i) * W4]);
        // compute + store current batch
        #pragma unroll
        for (int i = 0; i < U; ++i) {
            m = fmax4(m, cur[i]);
            __builtin_nontemporal_store(m, &op[(hbase - i) * W4]);
        }
        #pragma unroll
        for (int i = 0; i < U; ++i) cur[i] = nxt[i];
    }

    // epilogue: last batch (h = 7..0)
    #pragma unroll
    for (int i = 0; i < U; ++i) {
        m = fmax4(m, cur[i]);
        __builtin_nontemporal_store(m, &op[(U - 1 - i) * W4]);
    }
}

extern "C" void kernel_launch(void* const* d_in, const int* in_sizes, int n_in,
                              void* d_out, int out_size, void* d_ws, size_t ws_size,
                              hipStream_t stream) {
    const f32x4* x = (const f32x4*)d_in[0];
    f32x4* out = (f32x4*)d_out;

    const int total = 32 * 256 * W4;   // 262144 threads
    const int block = 256;
    const int grid = total / block;    // 1024
    toppool_kernel<<<grid, block, 0, stream>>>(x, out);
}